// Round 8
// baseline (524.268 us; speedup 1.0000x reference)
//
#include <hip/hip_runtime.h>
#include <hip/hip_bf16.h>

#define NPTS 131072
// transposed feature region float offsets in ft:
//   ft0 @ 0 (56*56*64=200704), ft1 @ 200704 (28*28*128=100352),
//   ft2 @ 301056 (14*14*256=50176), ft3 @ 351232 (7*7*512=25088)
#define FT_TOTAL 376320

// float4-unit offsets into ft (floats/4)
#define FT1_F4 50176
#define FT2_F4 75264
#define FT3_F4 87808

#define NB_T3 512   // blocks per scale3 slice (x2 slices)
#define NB_T2 128   // blocks per scale2 slice (x4 slices)
#define NB_T6 512   // blocks for scale0+scale1
#define GRID_GATHER (2*NB_T3 + 4*NB_T2 + NB_T6)   // 2048

typedef float f32x4 __attribute__((ext_vector_type(4)));

// ------------------------------------------------------------------
// Kernel 1: per-point projection -> per-scale spatial index (or -1).
// Numerics verified absmax==0.0 (rounds 2/4/5/6).
// ------------------------------------------------------------------
__global__ __launch_bounds__(256) void k_indices(
    const float* __restrict__ pts,
    int4* __restrict__ idx4)
{
    int n = blockIdx.x * 256 + threadIdx.x;
    if (n >= NPTS) return;
    float px = pts[3 * n + 0];
    float py = pts[3 * n + 1];
    float pz = pts[3 * n + 2];
    float qh = __fdiv_rn(py, pz);
    float qw = __fdiv_rn(px, -pz);
    float h = __fadd_rn(__fmul_rn(248.0f, qh), 111.5f);
    float w = __fadd_rn(__fmul_rn(248.0f, qw), 111.5f);
    h = fminf(fmaxf(h, 0.0f), 223.0f);
    w = fminf(fmaxf(w, 0.0f), 223.0f);

    const float scl[4] = {0.25f, 0.125f, 0.0625f, 0.03125f};
    const int   S[4]   = {56, 28, 14, 7};
    int r[4];
#pragma unroll
    for (int s = 0; s < 4; ++s) {
        float x = h * scl[s];
        float y = w * scl[s];
        int x1 = (int)floorf(x);
        int x2 = min((int)ceilf(x), S[s] - 1);
        int y1 = (int)floorf(y);
        int y2 = min((int)ceilf(y), S[s] - 1);
        int bit = (x2 - x1) * (y2 - y1);
        r[s] = bit ? (x1 * S[s] + y1) : -1;
    }
    idx4[n] = make_int4(r[0], r[1], r[2], r[3]);
}

// ------------------------------------------------------------------
// Kernel 2: transpose feat[b] [C,H,W] -> [H*W, C]. 1.5 MB, trivial.
// ------------------------------------------------------------------
__global__ __launch_bounds__(256) void k_transpose(
    const float* __restrict__ f0,
    const float* __restrict__ f1,
    const float* __restrict__ f2,
    const float* __restrict__ f3,
    const int* __restrict__ batch,
    float* __restrict__ ft)
{
    int d = blockIdx.x * 256 + threadIdx.x;
    if (d >= FT_TOTAL) return;
    int b = *batch;
    const float* src;
    int local, c, p, hw;
    if (d < 200704) {
        local = d;          c = local & 63;  p = local >> 6; hw = 3136;
        src = f0 + (size_t)b * 64 * 3136;
    } else if (d < 301056) {
        local = d - 200704; c = local & 127; p = local >> 7; hw = 784;
        src = f1 + (size_t)b * 128 * 784;
    } else if (d < 351232) {
        local = d - 301056; c = local & 255; p = local >> 8; hw = 196;
        src = f2 + (size_t)b * 256 * 196;
    } else {
        local = d - 351232; c = local & 511; p = local >> 9; hw = 49;
        src = f3 + (size_t)b * 512 * 49;
    }
    ft[d] = src[c * hw + p];
}

// ------------------------------------------------------------------
// Kernel 3: fused gather, one dispatch, 3 block families.
//  - scale3 (53% of bytes): 2 channel-slices of 50 KB staged in LDS;
//    each wave stores one point's 1 KiB slice (contiguous).
//  - scale2 (27%): 4 channel-slices of 50 KB in LDS; wave stores
//    4 points x 256 B aligned segments.
//  - scale0+1 (20%): global reads (worst case ~100 MB HBM), linear
//    thread->address mapping -> perfectly dense stores.
// All stores non-temporal. LDS reads are immune to L2 thrash by the
// 503 MB store stream — removes ~400 MB of HBM read traffic.
// ------------------------------------------------------------------
__global__ __launch_bounds__(256) void k_gather(
    const int4* __restrict__ idx,
    const float* __restrict__ ft,
    float* __restrict__ out)
{
    __shared__ float lds[12544];           // 50176 B
    const f32x4* ft4 = (const f32x4*)ft;
    f32x4* lds4 = (f32x4*)lds;
    f32x4* out4 = (f32x4*)out;
    int bid = blockIdx.x;
    int tid = threadIdx.x;

    if (bid < 2 * NB_T3) {
        // ---- scale3, slice s: channels 256s..256s+255 ----
        int s = bid / NB_T3;
        int blk = bid - s * NB_T3;
        for (int i = tid; i < 3136; i += 256) {          // 49 rows x 64 f4
            int r = i >> 6, c4 = i & 63;
            lds4[i] = ft4[FT3_F4 + r * 128 + 64 * s + c4];
        }
        __syncthreads();
        int wave = tid >> 6, lane = tid & 63;
        for (int p = blk * 4 + wave; p < NPTS; p += NB_T3 * 4) {
            int id = idx[p].w;                           // broadcast load
            f32x4 v = (f32x4)(0.0f);
            if (id >= 0) v = lds4[id * 64 + lane];       // dense 1 KiB
            __builtin_nontemporal_store(v, &out4[p * 240 + 112 + s * 64 + lane]);
        }
    } else if (bid < 2 * NB_T3 + 4 * NB_T2) {
        // ---- scale2, slice s: channels 64s..64s+63 ----
        int rem = bid - 2 * NB_T3;
        int s = rem / NB_T2;
        int blk = rem - s * NB_T2;
        for (int i = tid; i < 3136; i += 256) {          // 196 rows x 16 f4
            int r = i >> 4, c4 = i & 15;
            lds4[i] = ft4[FT2_F4 + r * 64 + 16 * s + c4];
        }
        __syncthreads();
        int wave = tid >> 6, lane = tid & 63;
        int sub = lane >> 4, c = lane & 15;              // 4 points per wave
        for (int p0 = blk * 16 + wave * 4; p0 < NPTS; p0 += NB_T2 * 16) {
            int p = p0 + sub;
            int id = idx[p].z;
            f32x4 v = (f32x4)(0.0f);
            if (id >= 0) v = lds4[id * 16 + c];
            __builtin_nontemporal_store(v, &out4[p * 240 + 48 + s * 16 + c]);
        }
    } else {
        // ---- scale0 + scale1: chunks c=0..47 of each row ----
        int blk = bid - (2 * NB_T3 + 4 * NB_T2);
        const int TOT = NPTS * 48;                       // 6291456
        for (int u = blk * 256 + tid; u < TOT; u += NB_T6 * 256) {
            int p = u / 48;                              // magic-mul
            int c = u - p * 48;
            int2 q = *(const int2*)&idx[p];              // (scale0, scale1)
            f32x4 v = (f32x4)(0.0f);
            if (c < 16) {
                if (q.x >= 0) v = ft4[q.x * 16 + c];
            } else {
                // FT1_F4 is ALREADY in float4 units (round-6 bug: /4 again)
                if (q.y >= 0) v = ft4[FT1_F4 + q.y * 32 + (c - 16)];
            }
            __builtin_nontemporal_store(v, &out4[p * 240 + c]);
        }
    }
}

extern "C" void kernel_launch(void* const* d_in, const int* in_sizes, int n_in,
                              void* d_out, int out_size, void* d_ws, size_t ws_size,
                              hipStream_t stream) {
    const float* f0  = (const float*)d_in[0];
    const float* f1  = (const float*)d_in[1];
    const float* f2  = (const float*)d_in[2];
    const float* f3  = (const float*)d_in[3];
    const float* pts = (const float*)d_in[4];
    const int* batch = (const int*)d_in[5];

    // ws layout: [ int4 idx[NPTS] : 2 MiB ][ f32 ft[FT_TOTAL] : 1.44 MiB ]
    int4* idx4 = (int4*)d_ws;
    float* ft = (float*)((char*)d_ws + (size_t)NPTS * 16);
    float* out = (float*)d_out;

    k_indices<<<NPTS / 256, 256, 0, stream>>>(pts, idx4);
    k_transpose<<<(FT_TOTAL + 255) / 256, 256, 0, stream>>>(f0, f1, f2, f3, batch, ft);
    k_gather<<<GRID_GATHER, 256, 0, stream>>>(idx4, ft, out);
}